// Round 4
// baseline (438.404 us; speedup 1.0000x reference)
//
#include <hip/hip_runtime.h>
#include <hip/hip_cooperative_groups.h>

namespace cg = cooperative_groups;

#define DIMN 32
#define HD   32
#define FN   16
#define FE   8
#define NG   64
#define MB   8    // nodes register-blocked per pass in K1
#define NPB  32   // nodes per block in K1

// K1: per-node precompute, register-blocked over MB nodes so each s_nnw LDS
// read is reused MB times. Also zeroes agg and u (replaces memsets).
//   out[n,d]  = relu(x[n,:] @ lin0_w[d,:] + lin0_b[d])
//   G[n,h,f]  = sum_d out[n,d] * nn_w[d*256 + h*8 + f]
//   bmsg[n,h] = sum_d out[n,d] * nn_b[d*32 + h]
__global__ __launch_bounds__(256) void k1_node_pre(
    const float* __restrict__ x, const float* __restrict__ lin0_w,
    const float* __restrict__ lin0_b, const float* __restrict__ nn_w,
    const float* __restrict__ nn_b,
    float* __restrict__ outn, float* __restrict__ G, float* __restrict__ bmsg,
    float* __restrict__ agg, float* __restrict__ u, int N)
{
    __shared__ float s_nnw[DIMN * HD * FE];  // 32 KB, layout d*256 + (h*8+f)
    __shared__ float s_nnb[DIMN * HD];       // 4 KB
    __shared__ float s_l0wT[FN * DIMN];      // transposed: [j*32+d]
    __shared__ float s_l0b[DIMN];
    __shared__ float s_x[MB * FN];
    __shared__ float s_out[MB * DIMN];

    const int tid = threadIdx.x;

    // zero agg (N*32) and u (2048) via grid-stride
    for (int i = blockIdx.x * 256 + tid; i < N * HD; i += gridDim.x * 256)
        agg[i] = 0.f;
    if (blockIdx.x == 0)
        for (int i = tid; i < NG * HD; i += 256) u[i] = 0.f;

    for (int i = tid; i < DIMN * HD * FE; i += 256) s_nnw[i] = nn_w[i];
    for (int i = tid; i < DIMN * HD; i += 256)      s_nnb[i] = nn_b[i];
    // FN*DIMN = 512 elements -> MUST be a strided loop with 256 threads
    // (R3 bug: single-condition load left d=16..31 uninitialized)
    for (int i = tid; i < FN * DIMN; i += 256)
        s_l0wT[(i & 15) * DIMN + (i >> 4)] = lin0_w[i];
    if (tid < DIMN) s_l0b[tid] = lin0_b[tid];
    __syncthreads();

    const int n0 = blockIdx.x * NPB;
    const int n1 = min(n0 + NPB, N);
    const int m = tid >> 5, d = tid & 31;

    for (int nb = n0; nb < n1; nb += MB) {
        const int cnt = min(MB, n1 - nb);
        if (tid < cnt * FN) s_x[tid] = x[(size_t)nb * FN + tid];
        __syncthreads();

        // lin0 + relu: thread (m,d) computes out[nb+m, d]
        if (m < cnt) {
            float s = s_l0b[d];
            #pragma unroll
            for (int j = 0; j < FN; ++j)
                s = fmaf(s_x[m * FN + j], s_l0wT[j * DIMN + d], s);
            s = fmaxf(s, 0.f);
            s_out[m * DIMN + d] = s;
            outn[(size_t)(nb + m) * DIMN + d] = s;
        }
        __syncthreads();

        // G for MB nodes at once: one s_nnw read feeds MB FMAs
        float g[MB];
        #pragma unroll
        for (int mm = 0; mm < MB; ++mm) g[mm] = 0.f;
        for (int dd = 0; dd < DIMN; ++dd) {
            const float w = s_nnw[dd * 256 + tid];
            #pragma unroll
            for (int mm = 0; mm < MB; ++mm)
                g[mm] = fmaf(s_out[mm * DIMN + dd], w, g[mm]);
        }
        #pragma unroll
        for (int mm = 0; mm < MB; ++mm)
            if (mm < cnt) G[(size_t)(nb + mm) * 256 + tid] = g[mm];

        // bmsg: thread (m,h=d)
        if (m < cnt) {
            float b = 0.f;
            #pragma unroll 8
            for (int dd = 0; dd < DIMN; ++dd)
                b = fmaf(s_out[m * DIMN + dd], s_nnb[dd * HD + d], b);
            bmsg[(size_t)(nb + m) * HD + d] = b;
        }
        __syncthreads();
    }
}

// Kcoop: phase B (edge-parallel message + atomic scatter) -> grid.sync ->
//        phase C (root update + pool atomics) -> grid.sync -> phase D (head).
__global__ __launch_bounds__(256, 8) void kcoop(
    const int* __restrict__ ei, const float* __restrict__ ea,
    const float* __restrict__ G, const float* __restrict__ bmsg,
    const float* __restrict__ outn, const float* __restrict__ root_w,
    const float* __restrict__ conv_b, const int* __restrict__ batch,
    const float* __restrict__ lin1_w, const float* __restrict__ lin1_b,
    const float* __restrict__ lin2_w, const float* __restrict__ lin2_b,
    float* __restrict__ agg, float* __restrict__ u, float* __restrict__ outp,
    int N, int E)
{
    __shared__ float s_rw[DIMN * HD];
    __shared__ float s_cb[HD];
    const int tid = threadIdx.x;
    for (int i = tid; i < DIMN * HD; i += 256) s_rw[i] = root_w[i];
    if (tid < HD) s_cb[tid] = conv_b[tid];
    __syncthreads();

    const long stride = (long)gridDim.x * 256;

    // ---- phase B: one (edge, h) per work-item, grid-stride ----
    for (long t = (long)blockIdx.x * 256 + tid; t < (long)E * HD; t += stride) {
        const int e = (int)(t >> 5);
        const int h = (int)(t & 31);
        const int src = ei[e];
        const int dst = ei[E + e];
        const float* gp = G + (size_t)src * 256 + h * 8;
        const float4 ga = *(const float4*)(gp);
        const float4 gb = *(const float4*)(gp + 4);
        const float4 e0 = *(const float4*)(ea + (size_t)e * FE);
        const float4 e1 = *(const float4*)(ea + (size_t)e * FE + 4);
        float msg = bmsg[(size_t)src * HD + h];
        msg = fmaf(e0.x, ga.x, msg);
        msg = fmaf(e0.y, ga.y, msg);
        msg = fmaf(e0.z, ga.z, msg);
        msg = fmaf(e0.w, ga.w, msg);
        msg = fmaf(e1.x, gb.x, msg);
        msg = fmaf(e1.y, gb.y, msg);
        msg = fmaf(e1.z, gb.z, msg);
        msg = fmaf(e1.w, gb.w, msg);
        atomicAdd(agg + (size_t)dst * HD + h, msg);
    }

    cg::this_grid().sync();

    // ---- phase C: h = relu(agg + out@root_w + conv_b), pool into u ----
    for (int t = blockIdx.x * 256 + tid; t < N * HD; t += (int)stride) {
        const int n = t >> 5;
        const int h = t & 31;
        float v = agg[t] + s_cb[h];
        const float* orow = outn + (size_t)n * DIMN;
        #pragma unroll 8
        for (int k = 0; k < DIMN; ++k)
            v = fmaf(orow[k], s_rw[k * HD + h], v);
        v = fmaxf(v, 0.f);
        atomicAdd(u + (size_t)batch[n] * HD + h, v);
    }

    cg::this_grid().sync();

    // ---- phase D: head MLP, one thread per graph ----
    if (blockIdx.x == 0 && tid < NG) {
        const int g = tid;
        float ur[HD];
        #pragma unroll
        for (int hh = 0; hh < HD; ++hh) ur[hh] = u[(size_t)g * HD + hh];
        float acc = lin2_b[0];
        #pragma unroll
        for (int i = 0; i < 16; ++i) {
            float o = lin1_b[i];
            #pragma unroll
            for (int hh = 0; hh < HD; ++hh)
                o = fmaf(ur[hh], lin1_w[i * HD + hh], o);
            o = fmaxf(o, 0.f);
            acc = fmaf(o, lin2_w[i], acc);
        }
        outp[g] = acc;
    }
}

extern "C" void kernel_launch(void* const* d_in, const int* in_sizes, int n_in,
                              void* d_out, int out_size, void* d_ws, size_t ws_size,
                              hipStream_t stream)
{
    const float* x      = (const float*)d_in[0];
    const int*   ei     = (const int*)  d_in[1];
    const float* ea     = (const float*)d_in[2];
    const int*   batch  = (const int*)  d_in[3];
    const float* lin0_w = (const float*)d_in[4];
    const float* lin0_b = (const float*)d_in[5];
    const float* nn_w   = (const float*)d_in[6];
    const float* nn_b   = (const float*)d_in[7];
    const float* root_w = (const float*)d_in[8];
    const float* conv_b = (const float*)d_in[9];
    const float* lin1_w = (const float*)d_in[10];
    const float* lin1_b = (const float*)d_in[11];
    const float* lin2_w = (const float*)d_in[12];
    const float* lin2_b = (const float*)d_in[13];

    const int N = in_sizes[0] / FN;   // 12500
    const int E = in_sizes[2] / FE;   // 200000

    float* ws   = (float*)d_ws;
    float* outn = ws;                          // N*32
    float* G    = outn + (size_t)N * DIMN;     // N*256
    float* bmsg = G    + (size_t)N * 256;      // N*32
    float* agg  = bmsg + (size_t)N * DIMN;     // N*32
    float* u    = agg  + (size_t)N * DIMN;     // 64*32
    float* outp = (float*)d_out;

    const int nb1 = (N + NPB - 1) / NPB;
    k1_node_pre<<<nb1, 256, 0, stream>>>(x, lin0_w, lin0_b, nn_w, nn_b,
                                         outn, G, bmsg, agg, u, N);

    // occupancy-sized cooperative launch (co-residency required)
    int maxBlocksPerCU = 0;
    hipOccupancyMaxActiveBlocksPerMultiprocessor(&maxBlocksPerCU,
        reinterpret_cast<const void*>(kcoop), 256, 0);
    if (maxBlocksPerCU < 1) maxBlocksPerCU = 1;
    int nblk = maxBlocksPerCU * 256;           // 256 CUs on MI355X
    const long work = (long)E * HD / 256;      // items per thread-slot target
    if ((long)nblk > work) nblk = (int)work;
    if (nblk > 2048) nblk = 2048;

    int Nl = N, El = E;
    void* args[] = {
        (void*)&ei, (void*)&ea, (void*)&G, (void*)&bmsg, (void*)&outn,
        (void*)&root_w, (void*)&conv_b, (void*)&batch,
        (void*)&lin1_w, (void*)&lin1_b, (void*)&lin2_w, (void*)&lin2_b,
        (void*)&agg, (void*)&u, (void*)&outp, (void*)&Nl, (void*)&El
    };
    hipLaunchCooperativeKernel(reinterpret_cast<const void*>(kcoop),
                               dim3(nblk), dim3(256), args, 0, stream);
}

// Round 5
// 250.329 us; speedup vs baseline: 1.7513x; 1.7513x over previous
//
#include <hip/hip_runtime.h>

#define DIMN 32
#define HD   32
#define FN   16
#define FE   8
#define NG   64
#define MB   8    // nodes register-blocked per pass in K1
#define NPB  32   // nodes per block in K1

// K1: per-node precompute; also zeroes agg, u, ticket (replaces memsets).
//   out[n,d]  = relu(x[n,:] @ lin0_w[d,:] + lin0_b[d])
//   G[n,h,f]  = sum_d out[n,d] * nn_w[d*256 + h*8 + f]
//   bmsg[n,h] = sum_d out[n,d] * nn_b[d*32 + h]
__global__ __launch_bounds__(256) void k1_node_pre(
    const float* __restrict__ x, const float* __restrict__ lin0_w,
    const float* __restrict__ lin0_b, const float* __restrict__ nn_w,
    const float* __restrict__ nn_b,
    float* __restrict__ outn, float* __restrict__ G, float* __restrict__ bmsg,
    float* __restrict__ agg, float* __restrict__ u, int* __restrict__ ticket,
    int N)
{
    __shared__ float s_nnw[DIMN * HD * FE];  // 32 KB, layout d*256 + (h*8+f)
    __shared__ float s_nnb[DIMN * HD];       // 4 KB
    __shared__ float s_l0wT[FN * DIMN];      // transposed: [j*32+d]
    __shared__ float s_l0b[DIMN];
    __shared__ float s_x[MB * FN];
    __shared__ float s_out[MB * DIMN];

    const int tid = threadIdx.x;

    // zero agg (N*32), u (2048), ticket — grid-stride
    for (int i = blockIdx.x * 256 + tid; i < N * HD; i += gridDim.x * 256)
        agg[i] = 0.f;
    if (blockIdx.x == 0) {
        for (int i = tid; i < NG * HD; i += 256) u[i] = 0.f;
        if (tid == 0) *ticket = 0;
    }

    for (int i = tid; i < DIMN * HD * FE; i += 256) s_nnw[i] = nn_w[i];
    for (int i = tid; i < DIMN * HD; i += 256)      s_nnb[i] = nn_b[i];
    // FN*DIMN = 512 elements -> strided loop (256 threads)
    for (int i = tid; i < FN * DIMN; i += 256)
        s_l0wT[(i & 15) * DIMN + (i >> 4)] = lin0_w[i];
    if (tid < DIMN) s_l0b[tid] = lin0_b[tid];
    __syncthreads();

    const int n0 = blockIdx.x * NPB;
    const int n1 = min(n0 + NPB, N);
    const int m = tid >> 5, d = tid & 31;

    for (int nb = n0; nb < n1; nb += MB) {
        const int cnt = min(MB, n1 - nb);
        if (tid < cnt * FN) s_x[tid] = x[(size_t)nb * FN + tid];
        __syncthreads();

        if (m < cnt) {
            float s = s_l0b[d];
            #pragma unroll
            for (int j = 0; j < FN; ++j)
                s = fmaf(s_x[m * FN + j], s_l0wT[j * DIMN + d], s);
            s = fmaxf(s, 0.f);
            s_out[m * DIMN + d] = s;
            outn[(size_t)(nb + m) * DIMN + d] = s;
        }
        __syncthreads();

        // G for MB nodes at once: one s_nnw read feeds MB FMAs
        float g[MB];
        #pragma unroll
        for (int mm = 0; mm < MB; ++mm) g[mm] = 0.f;
        for (int dd = 0; dd < DIMN; ++dd) {
            const float w = s_nnw[dd * 256 + tid];
            #pragma unroll
            for (int mm = 0; mm < MB; ++mm)
                g[mm] = fmaf(s_out[mm * DIMN + dd], w, g[mm]);
        }
        #pragma unroll
        for (int mm = 0; mm < MB; ++mm)
            if (mm < cnt) G[(size_t)(nb + mm) * 256 + tid] = g[mm];

        if (m < cnt) {
            float b = 0.f;
            #pragma unroll 8
            for (int dd = 0; dd < DIMN; ++dd)
                b = fmaf(s_out[m * DIMN + dd], s_nnb[dd * HD + d], b);
            bmsg[(size_t)(nb + m) * HD + d] = b;
        }
        __syncthreads();
    }
}

// K2: per-edge message + scatter. 32 threads/edge, thread = h. Full VGPR
// budget (no min-waves bound) so the 4 float4 loads stay in flight.
__global__ __launch_bounds__(256) void k2_edge(
    const int* __restrict__ ei, const float* __restrict__ ea,
    const float* __restrict__ G, const float* __restrict__ bmsg,
    float* __restrict__ agg, int E)
{
    const int t = blockIdx.x * 256 + threadIdx.x;
    const int e = t >> 5;
    const int h = t & 31;
    if (e >= E) return;

    const int src = ei[e];
    const int dst = ei[E + e];

    const float* gp = G + (size_t)src * 256 + h * 8;
    const float4 ga = *(const float4*)(gp);
    const float4 gb = *(const float4*)(gp + 4);
    const float4 e0 = *(const float4*)(ea + (size_t)e * FE);
    const float4 e1 = *(const float4*)(ea + (size_t)e * FE + 4);

    float acc = bmsg[(size_t)src * HD + h];
    acc = fmaf(e0.x, ga.x, acc);
    acc = fmaf(e0.y, ga.y, acc);
    acc = fmaf(e0.z, ga.z, acc);
    acc = fmaf(e0.w, ga.w, acc);
    acc = fmaf(e1.x, gb.x, acc);
    acc = fmaf(e1.y, gb.y, acc);
    acc = fmaf(e1.z, gb.z, acc);
    acc = fmaf(e1.w, gb.w, acc);

    atomicAdd(agg + (size_t)dst * HD + h, acc);
}

// K3: h = relu(agg + out@root_w + conv_b); pool into u via atomics.
// Last block (ticket) runs the head MLP — replaces a 4th dispatch.
__global__ __launch_bounds__(256) void k3_node_head(
    const float* __restrict__ agg, const float* __restrict__ outn,
    const float* __restrict__ root_w, const float* __restrict__ conv_b,
    const int* __restrict__ batch,
    const float* __restrict__ lin1_w, const float* __restrict__ lin1_b,
    const float* __restrict__ lin2_w, const float* __restrict__ lin2_b,
    float* __restrict__ u, float* __restrict__ outp, int* __restrict__ ticket,
    int N)
{
    __shared__ float s_rw[DIMN * HD];
    __shared__ float s_cb[HD];
    const int tid = threadIdx.x;
    for (int i = tid; i < DIMN * HD; i += 256) s_rw[i] = root_w[i];
    if (tid < HD) s_cb[tid] = conv_b[tid];
    __syncthreads();

    const int t = blockIdx.x * 256 + tid;
    const int n = t >> 5;
    const int h = t & 31;
    if (n < N) {
        float v = agg[t] + s_cb[h];
        const float* orow = outn + (size_t)n * DIMN;
        #pragma unroll 8
        for (int k = 0; k < DIMN; ++k)
            v = fmaf(orow[k], s_rw[k * HD + h], v);
        v = fmaxf(v, 0.f);
        atomicAdd(u + (size_t)batch[n] * HD + h, v);
    }

    // ---- last-block-does-head ----
    __threadfence();               // make this block's u-atomics visible
    __syncthreads();
    __shared__ int s_last;
    if (tid == 0)
        s_last = (atomicAdd(ticket, 1) == gridDim.x - 1) ? 1 : 0;
    __syncthreads();
    if (!s_last) return;

    __threadfence();               // acquire: all other blocks' u-atomics done
    if (tid < NG) {
        const int g = tid;
        float ur[HD];
        #pragma unroll
        for (int hh = 0; hh < HD; ++hh)
            ur[hh] = __hip_atomic_load(u + (size_t)g * HD + hh,
                                       __ATOMIC_RELAXED, __HIP_MEMORY_SCOPE_AGENT);
        float acc = lin2_b[0];
        #pragma unroll
        for (int i = 0; i < 16; ++i) {
            float o = lin1_b[i];
            #pragma unroll
            for (int hh = 0; hh < HD; ++hh)
                o = fmaf(ur[hh], lin1_w[i * HD + hh], o);
            o = fmaxf(o, 0.f);
            acc = fmaf(o, lin2_w[i], acc);
        }
        outp[g] = acc;
    }
}

extern "C" void kernel_launch(void* const* d_in, const int* in_sizes, int n_in,
                              void* d_out, int out_size, void* d_ws, size_t ws_size,
                              hipStream_t stream)
{
    const float* x      = (const float*)d_in[0];
    const int*   ei     = (const int*)  d_in[1];
    const float* ea     = (const float*)d_in[2];
    const int*   batch  = (const int*)  d_in[3];
    const float* lin0_w = (const float*)d_in[4];
    const float* lin0_b = (const float*)d_in[5];
    const float* nn_w   = (const float*)d_in[6];
    const float* nn_b   = (const float*)d_in[7];
    const float* root_w = (const float*)d_in[8];
    const float* conv_b = (const float*)d_in[9];
    const float* lin1_w = (const float*)d_in[10];
    const float* lin1_b = (const float*)d_in[11];
    const float* lin2_w = (const float*)d_in[12];
    const float* lin2_b = (const float*)d_in[13];

    const int N = in_sizes[0] / FN;   // 12500
    const int E = in_sizes[2] / FE;   // 200000

    float* ws   = (float*)d_ws;
    float* outn = ws;                          // N*32
    float* G    = outn + (size_t)N * DIMN;     // N*256
    float* bmsg = G    + (size_t)N * 256;      // N*32
    float* agg  = bmsg + (size_t)N * DIMN;     // N*32
    float* u    = agg  + (size_t)N * DIMN;     // 64*32
    int*   tick = (int*)(u + NG * HD);
    float* outp = (float*)d_out;

    const int nb1 = (N + NPB - 1) / NPB;
    k1_node_pre<<<nb1, 256, 0, stream>>>(x, lin0_w, lin0_b, nn_w, nn_b,
                                         outn, G, bmsg, agg, u, tick, N);

    const int nb2 = (E * 32 + 255) / 256;
    k2_edge<<<nb2, 256, 0, stream>>>(ei, ea, G, bmsg, agg, E);

    const int nb3 = (N * 32 + 255) / 256;
    k3_node_head<<<nb3, 256, 0, stream>>>(agg, outn, root_w, conv_b, batch,
                                          lin1_w, lin1_b, lin2_w, lin2_b,
                                          u, outp, tick, N);
}

// Round 6
// 177.536 us; speedup vs baseline: 2.4694x; 1.4100x over previous
//
#include <hip/hip_runtime.h>

#define DIMN 32
#define HD   32
#define FN   16
#define FE   8
#define NG   64
#define MB   8    // nodes register-blocked per pass in K1
#define NPB  32   // nodes per block in K1

// K1: per-node precompute; also zeroes agg (replaces memset).
//   out[n,d]  = relu(x[n,:] @ lin0_w[d,:] + lin0_b[d])
//   G[n,h,f]  = sum_d out[n,d] * nn_w[d*256 + h*8 + f]
//   bmsg[n,h] = sum_d out[n,d] * nn_b[d*32 + h]
__global__ __launch_bounds__(256) void k1_node_pre(
    const float* __restrict__ x, const float* __restrict__ lin0_w,
    const float* __restrict__ lin0_b, const float* __restrict__ nn_w,
    const float* __restrict__ nn_b,
    float* __restrict__ outn, float* __restrict__ G, float* __restrict__ bmsg,
    float* __restrict__ agg, int N)
{
    __shared__ float s_nnw[DIMN * HD * FE];  // 32 KB, layout d*256 + (h*8+f)
    __shared__ float s_nnb[DIMN * HD];       // 4 KB
    __shared__ float s_l0wT[FN * DIMN];      // transposed: [j*32+d]
    __shared__ float s_l0b[DIMN];
    __shared__ float s_x[MB * FN];
    __shared__ float s_out[MB * DIMN];

    const int tid = threadIdx.x;

    // zero agg (N*32) — grid-stride
    for (int i = blockIdx.x * 256 + tid; i < N * HD; i += gridDim.x * 256)
        agg[i] = 0.f;

    for (int i = tid; i < DIMN * HD * FE; i += 256) s_nnw[i] = nn_w[i];
    for (int i = tid; i < DIMN * HD; i += 256)      s_nnb[i] = nn_b[i];
    // FN*DIMN = 512 elements -> strided loop (256 threads)
    for (int i = tid; i < FN * DIMN; i += 256)
        s_l0wT[(i & 15) * DIMN + (i >> 4)] = lin0_w[i];
    if (tid < DIMN) s_l0b[tid] = lin0_b[tid];
    __syncthreads();

    const int n0 = blockIdx.x * NPB;
    const int n1 = min(n0 + NPB, N);
    const int m = tid >> 5, d = tid & 31;

    for (int nb = n0; nb < n1; nb += MB) {
        const int cnt = min(MB, n1 - nb);
        if (tid < cnt * FN) s_x[tid] = x[(size_t)nb * FN + tid];
        __syncthreads();

        if (m < cnt) {
            float s = s_l0b[d];
            #pragma unroll
            for (int j = 0; j < FN; ++j)
                s = fmaf(s_x[m * FN + j], s_l0wT[j * DIMN + d], s);
            s = fmaxf(s, 0.f);
            s_out[m * DIMN + d] = s;
            outn[(size_t)(nb + m) * DIMN + d] = s;
        }
        __syncthreads();

        // G for MB nodes at once: one s_nnw read feeds MB FMAs
        float g[MB];
        #pragma unroll
        for (int mm = 0; mm < MB; ++mm) g[mm] = 0.f;
        for (int dd = 0; dd < DIMN; ++dd) {
            const float w = s_nnw[dd * 256 + tid];
            #pragma unroll
            for (int mm = 0; mm < MB; ++mm)
                g[mm] = fmaf(s_out[mm * DIMN + dd], w, g[mm]);
        }
        #pragma unroll
        for (int mm = 0; mm < MB; ++mm)
            if (mm < cnt) G[(size_t)(nb + mm) * 256 + tid] = g[mm];

        if (m < cnt) {
            float b = 0.f;
            #pragma unroll 8
            for (int dd = 0; dd < DIMN; ++dd)
                b = fmaf(s_out[m * DIMN + dd], s_nnb[dd * HD + d], b);
            bmsg[(size_t)(nb + m) * HD + d] = b;
        }
        __syncthreads();
    }
}

// K2: per-edge message + scatter. 32 threads/edge, thread = h. Full VGPR
// budget (no min-waves bound) so the 4 float4 loads stay in flight.
__global__ __launch_bounds__(256) void k2_edge(
    const int* __restrict__ ei, const float* __restrict__ ea,
    const float* __restrict__ G, const float* __restrict__ bmsg,
    float* __restrict__ agg, int E)
{
    const int t = blockIdx.x * 256 + threadIdx.x;
    const int e = t >> 5;
    const int h = t & 31;
    if (e >= E) return;

    const int src = ei[e];
    const int dst = ei[E + e];

    const float* gp = G + (size_t)src * 256 + h * 8;
    const float4 ga = *(const float4*)(gp);
    const float4 gb = *(const float4*)(gp + 4);
    const float4 e0 = *(const float4*)(ea + (size_t)e * FE);
    const float4 e1 = *(const float4*)(ea + (size_t)e * FE + 4);

    float acc = bmsg[(size_t)src * HD + h];
    acc = fmaf(e0.x, ga.x, acc);
    acc = fmaf(e0.y, ga.y, acc);
    acc = fmaf(e0.z, ga.z, acc);
    acc = fmaf(e0.w, ga.w, acc);
    acc = fmaf(e1.x, gb.x, acc);
    acc = fmaf(e1.y, gb.y, acc);
    acc = fmaf(e1.z, gb.z, acc);
    acc = fmaf(e1.w, gb.w, acc);

    atomicAdd(agg + (size_t)dst * HD + h, acc);
}

// K3: hout = relu(agg + out@root_w + conv_b), written IN PLACE over agg.
// Pure streaming, no atomics, no fences.
__global__ __launch_bounds__(256) void k3_node_upd(
    float* __restrict__ agg, const float* __restrict__ outn,
    const float* __restrict__ root_w, const float* __restrict__ conv_b,
    int N)
{
    __shared__ float s_rw[DIMN * HD];
    __shared__ float s_cb[HD];
    const int tid = threadIdx.x;
    for (int i = tid; i < DIMN * HD; i += 256) s_rw[i] = root_w[i];
    if (tid < HD) s_cb[tid] = conv_b[tid];
    __syncthreads();

    const int t = blockIdx.x * 256 + tid;
    const int n = t >> 5;
    const int h = t & 31;
    if (n >= N) return;

    float v = agg[t] + s_cb[h];
    const float* orow = outn + (size_t)n * DIMN;
    #pragma unroll 8
    for (int k = 0; k < DIMN; ++k)
        v = fmaf(orow[k], s_rw[k * HD + h], v);
    agg[t] = fmaxf(v, 0.f);
}

// K4: pool (batch sorted -> contiguous per-graph ranges, no atomics) + head MLP.
__global__ __launch_bounds__(64) void k4_pool_head(
    const float* __restrict__ hout, const int* __restrict__ batch,
    const float* __restrict__ lin1_w, const float* __restrict__ lin1_b,
    const float* __restrict__ lin2_w, const float* __restrict__ lin2_b,
    float* __restrict__ outp, int N)
{
    const int g = blockIdx.x;
    const int tid = threadIdx.x;

    // uniform binary searches for this graph's node range
    int a = 0, b = N;
    while (a < b) { int m = (a + b) >> 1; if (batch[m] < g) a = m + 1; else b = m; }
    const int lo = a;
    b = N;
    while (a < b) { int m = (a + b) >> 1; if (batch[m] < g + 1) a = m + 1; else b = m; }
    const int hi = a;

    __shared__ float s_u[HD];
    __shared__ float s_o[16];

    const int h = tid & 31, half = tid >> 5;
    float s = 0.f;
    for (int n = lo + half; n < hi; n += 2)
        s += hout[(size_t)n * HD + h];
    s += __shfl_down(s, 32);
    if (tid < HD) s_u[tid] = s;
    __syncthreads();

    if (tid < 16) {
        float o = lin1_b[tid];
        #pragma unroll
        for (int k = 0; k < HD; ++k) o = fmaf(s_u[k], lin1_w[tid * HD + k], o);
        s_o[tid] = fmaxf(o, 0.f);
    }
    __syncthreads();

    if (tid == 0) {
        float acc = lin2_b[0];
        #pragma unroll
        for (int i = 0; i < 16; ++i) acc = fmaf(s_o[i], lin2_w[i], acc);
        outp[g] = acc;
    }
}

extern "C" void kernel_launch(void* const* d_in, const int* in_sizes, int n_in,
                              void* d_out, int out_size, void* d_ws, size_t ws_size,
                              hipStream_t stream)
{
    const float* x      = (const float*)d_in[0];
    const int*   ei     = (const int*)  d_in[1];
    const float* ea     = (const float*)d_in[2];
    const int*   batch  = (const int*)  d_in[3];
    const float* lin0_w = (const float*)d_in[4];
    const float* lin0_b = (const float*)d_in[5];
    const float* nn_w   = (const float*)d_in[6];
    const float* nn_b   = (const float*)d_in[7];
    const float* root_w = (const float*)d_in[8];
    const float* conv_b = (const float*)d_in[9];
    const float* lin1_w = (const float*)d_in[10];
    const float* lin1_b = (const float*)d_in[11];
    const float* lin2_w = (const float*)d_in[12];
    const float* lin2_b = (const float*)d_in[13];

    const int N = in_sizes[0] / FN;   // 12500
    const int E = in_sizes[2] / FE;   // 200000

    float* ws   = (float*)d_ws;
    float* outn = ws;                          // N*32
    float* G    = outn + (size_t)N * DIMN;     // N*256
    float* bmsg = G    + (size_t)N * 256;      // N*32
    float* agg  = bmsg + (size_t)N * DIMN;     // N*32 (becomes hout in-place)
    float* outp = (float*)d_out;

    const int nb1 = (N + NPB - 1) / NPB;
    k1_node_pre<<<nb1, 256, 0, stream>>>(x, lin0_w, lin0_b, nn_w, nn_b,
                                         outn, G, bmsg, agg, N);

    const int nb2 = (E * 32 + 255) / 256;
    k2_edge<<<nb2, 256, 0, stream>>>(ei, ea, G, bmsg, agg, E);

    const int nb3 = (N * 32 + 255) / 256;
    k3_node_upd<<<nb3, 256, 0, stream>>>(agg, outn, root_w, conv_b, N);

    k4_pool_head<<<NG, 64, 0, stream>>>(agg, batch, lin1_w, lin1_b,
                                        lin2_w, lin2_b, outp, N);
}